// Round 3
// baseline (269.767 us; speedup 1.0000x reference)
//
#include <hip/hip_runtime.h>
#include <stdint.h>

#define B_ 64
#define P_ 32768
#define O_ 16
#define PPT 4                 // priors per thread in match_kernel

constexpr float OVERLAP_THRESH = 0.5f;
constexpr int   NEG_POS_RATIO  = 3;
constexpr float VAR0 = 0.1f;
constexpr float VAR1 = 0.2f;

// ---------------------------------------------------------------------------
// Kernel 1: per (b, truth o) find best prior index = argmax_p IoU(truth, prior)
// Tie-break: first (lowest) prior index, matching jnp.argmax. Packed key:
// (float_bits(iou) << 32) | ~p  — iou >= 0 so float bits are monotonic.
// Block (0,0) also zeroes the num_pos/acc scratch region (replaces memset).
// ---------------------------------------------------------------------------
__global__ __launch_bounds__(256)
void best_prior_kernel(const float* __restrict__ priors,
                       const float* __restrict__ targets,
                       unsigned long long* __restrict__ bp_pack,
                       int* __restrict__ zero_region) {
    if (blockIdx.x == 0 && blockIdx.y == 0 && threadIdx.x < 128)
        zero_region[threadIdx.x] = 0;

    int o = blockIdx.x;
    int b = blockIdx.y;
    const float* t = targets + (size_t)(b * O_ + o) * 5;
    float tx0 = t[0], ty0 = t[1], tx1 = t[2], ty1 = t[3];
    float area_t = (tx1 - tx0) * (ty1 - ty0);

    unsigned long long best = 0ull;
    for (int p = threadIdx.x; p < P_; p += blockDim.x) {
        float4 pr = ((const float4*)priors)[p];
        float px0 = pr.x - pr.z * 0.5f, py0 = pr.y - pr.w * 0.5f;
        float px1 = pr.x + pr.z * 0.5f, py1 = pr.y + pr.w * 0.5f;
        float area_p = (px1 - px0) * (py1 - py0);
        float ltx = fmaxf(tx0, px0), lty = fmaxf(ty0, py0);
        float rbx = fminf(tx1, px1), rby = fminf(ty1, py1);
        float w = fmaxf(rbx - ltx, 0.f), h = fmaxf(rby - lty, 0.f);
        float inter = w * h;
        float iou = inter / (area_t + area_p - inter);
        unsigned long long pack =
            ((unsigned long long)__float_as_uint(iou) << 32) | (unsigned)(~p);
        best = pack > best ? pack : best;
    }
    for (int off = 32; off; off >>= 1) {
        unsigned long long other = __shfl_down(best, off, 64);
        best = other > best ? other : best;
    }
    __shared__ unsigned long long s[4];
    int wid = threadIdx.x >> 6;
    if ((threadIdx.x & 63) == 0) s[wid] = best;
    __syncthreads();
    if (threadIdx.x == 0) {
        int nw = blockDim.x >> 6;
        for (int i = 1; i < nw; ++i) best = s[i] > best ? s[i] : best;
        bp_pack[b * O_ + o] = best;
    }
}

// ---------------------------------------------------------------------------
// Kernel 2: per (b, prior p): match, encode, smooth-L1, CE, rank_src.
// Division-free: argmax via cross-multiplication (iou_a>iou_b <=>
// inter_a*union_b > inter_b*union_a), threshold via 2*inter >= union.
// Truths-outer / priors-inner loop: LDS broadcasts amortized over PPT,
// 4 independent compare-update chains for ILP.
// ---------------------------------------------------------------------------
__device__ __forceinline__ float sl1(float d) {
    float ad = fabsf(d);
    return (ad < 1.f) ? 0.5f * d * d : ad - 0.5f;
}

__global__ __launch_bounds__(256)
void match_kernel(const float* __restrict__ loc_data,
                  const float* __restrict__ conf_data,
                  const float* __restrict__ priors,
                  const float* __restrict__ targets,
                  const unsigned long long* __restrict__ bp_pack,
                  float* __restrict__ rank,
                  int* __restrict__ num_pos,
                  double* __restrict__ acc) {
    int b = blockIdx.y;
    int p0 = blockIdx.x * (256 * PPT) + threadIdx.x;

    __shared__ float tr[O_][5];   // x0,y0,x1,y1,area
    __shared__ int   bpidx[O_];
    if (threadIdx.x < O_) {
        const float* t = targets + (size_t)(b * O_ + threadIdx.x) * 5;
        float x0 = t[0], y0 = t[1], x1 = t[2], y1 = t[3];
        tr[threadIdx.x][0] = x0; tr[threadIdx.x][1] = y0;
        tr[threadIdx.x][2] = x1; tr[threadIdx.x][3] = y1;
        tr[threadIdx.x][4] = (x1 - x0) * (y1 - y0);
        unsigned long long pk = bp_pack[b * O_ + threadIdx.x];
        bpidx[threadIdx.x] = (int)(~(unsigned)(pk & 0xffffffffull));
    }
    __syncthreads();

    // per-prior state
    float px0[PPT], py0[PPT], px1[PPT], py1[PPT], pa[PPT];
    float cx[PPT], cy[PPT], pz[PPT], pw[PPT];
    float2 cd[PPT];
    float ib[PPT], ub[PPT];
    int   idx[PPT], fidx[PPT];
    bool  fset[PPT];

    #pragma unroll
    for (int j = 0; j < PPT; ++j) {
        int p = p0 + j * 256;
        float4 pr = ((const float4*)priors)[p];
        cd[j] = ((const float2*)conf_data)[(size_t)b * P_ + p];
        cx[j] = pr.x; cy[j] = pr.y; pz[j] = pr.z; pw[j] = pr.w;
        px0[j] = pr.x - pr.z * 0.5f; py0[j] = pr.y - pr.w * 0.5f;
        px1[j] = pr.x + pr.z * 0.5f; py1[j] = pr.y + pr.w * 0.5f;
        pa[j]  = (px1[j] - px0[j]) * (py1[j] - py0[j]);
        ib[j] = 0.f; ub[j] = 1.f; idx[j] = 0; fidx[j] = 0; fset[j] = false;
    }

    #pragma unroll
    for (int o = 0; o < O_; ++o) {
        float tx0 = tr[o][0], ty0 = tr[o][1];
        float tx1 = tr[o][2], ty1 = tr[o][3], ta = tr[o][4];
        int bp = bpidx[o];
        #pragma unroll
        for (int j = 0; j < PPT; ++j) {
            float w = fmaxf(fminf(tx1, px1[j]) - fmaxf(tx0, px0[j]), 0.f);
            float h = fmaxf(fminf(ty1, py1[j]) - fmaxf(ty0, py0[j]), 0.f);
            float in_ = w * h;
            float un_ = ta + pa[j] - in_;
            bool gt = in_ * ub[j] > ib[j] * un_;
            ib[j]  = gt ? in_ : ib[j];
            ub[j]  = gt ? un_ : ub[j];
            idx[j] = gt ? o : idx[j];
            bool hit = (bp == p0 + j * 256);
            fidx[j] = hit ? o : fidx[j];
            fset[j] |= hit;
        }
    }

    double lld = 0.0, ce_pos = 0.0;
    int pc = 0;

    #pragma unroll
    for (int j = 0; j < PPT; ++j) {
        int p = p0 + j * 256;
        size_t gi = (size_t)b * P_ + p;
        bool pos = fset[j] || (2.0f * ib[j] >= ub[j]);
        int mi = fset[j] ? fidx[j] : idx[j];

        // CE from 2-class logits: lse - c_gt
        float m   = fmaxf(cd[j].x, cd[j].y);
        float ad  = fabsf(cd[j].x - cd[j].y);
        float lse = m + __logf(1.0f + __expf(-ad));
        float cgt = pos ? cd[j].y : cd[j].x;
        float ce  = lse - cgt;

        rank[gi] = pos ? 0.f : ce;

        if (pos) {
            float mx0 = tr[mi][0], my0 = tr[mi][1];
            float mx1 = tr[mi][2], my1 = tr[mi][3];
            float gcx = ((mx0 + mx1) * 0.5f - cx[j]) / (VAR0 * pz[j]);
            float gcy = ((my0 + my1) * 0.5f - cy[j]) / (VAR0 * pw[j]);
            float gw  = __logf((mx1 - mx0) / pz[j]) * (1.0f / VAR1);
            float gh  = __logf((my1 - my0) / pw[j]) * (1.0f / VAR1);
            float4 ld = ((const float4*)loc_data)[gi];
            float ll = sl1(ld.x - gcx) + sl1(ld.y - gcy) +
                       sl1(ld.z - gw)  + sl1(ld.w - gh);
            lld    += (double)ll;
            ce_pos += (double)ce;
            pc     += 1;
        }
    }

    for (int off = 32; off; off >>= 1) {
        lld    += __shfl_down(lld, off, 64);
        ce_pos += __shfl_down(ce_pos, off, 64);
        pc     += __shfl_down(pc, off, 64);
    }
    __shared__ double sll[4], sce[4];
    __shared__ int    spc[4];
    int wid = threadIdx.x >> 6;
    if ((threadIdx.x & 63) == 0) { sll[wid] = lld; sce[wid] = ce_pos; spc[wid] = pc; }
    __syncthreads();
    if (threadIdx.x == 0) {
        double tl = sll[0] + sll[1] + sll[2] + sll[3];
        double tc = sce[0] + sce[1] + sce[2] + sce[3];
        int    tp = spc[0] + spc[1] + spc[2] + spc[3];
        if (tl != 0.0) atomicAdd(&acc[0], tl);
        if (tc != 0.0) atomicAdd(&acc[1], tc);
        if (tp)        atomicAdd(&num_pos[b], tp);
    }
}

// ---------------------------------------------------------------------------
// Kernel 3: per batch, exact top-k sum of rank_src via 8-bit radix select.
// Keys register-resident (32/thread). Histogram counting uses wave-aggregated
// atomics (ballot -> one LDS atomic per distinct bin per wave) to avoid
// same-address LDS atomic serialization on the few hot exponent bins.
// ---------------------------------------------------------------------------
__global__ __launch_bounds__(1024)
void topk_kernel(const float* __restrict__ rank,
                 const int* __restrict__ num_pos,
                 double* __restrict__ acc) {
    int b  = blockIdx.x;
    int np = num_pos[b];
    int k  = min(NEG_POS_RATIO * np, P_ - 1);
    if (k <= 0) return;

    const uint4* r4 = (const uint4*)(rank + (size_t)b * P_);
    unsigned key[32];
    #pragma unroll
    for (int j = 0; j < 8; ++j) {
        uint4 v = r4[j * 1024 + threadIdx.x];
        key[j * 4 + 0] = v.x; key[j * 4 + 1] = v.y;
        key[j * 4 + 2] = v.z; key[j * 4 + 3] = v.w;
    }

    __shared__ unsigned cnt[256];
    __shared__ unsigned s_prefix;
    __shared__ int      s_k;
    int lane = threadIdx.x & 63;

    unsigned prefix = 0;
    int kk = k;
    for (int level = 0; level < 4; ++level) {
        int shift = 24 - level * 8;
        if (threadIdx.x < 256) cnt[threadIdx.x] = 0;
        __syncthreads();
        unsigned hi_mask = (level == 0) ? 0u : (0xffffffffu << (shift + 8));
        #pragma unroll
        for (int j = 0; j < 32; ++j) {
            unsigned u = key[j];
            bool act = (u & hi_mask) == prefix;
            unsigned bin = (u >> shift) & 255;
            unsigned long long mask = __ballot(act);
            while (mask) {
                int leader = __ffsll((unsigned long long)mask) - 1;
                unsigned lbin = __shfl(bin, leader, 64);
                unsigned long long mt = __ballot(act && bin == lbin);
                if (lane == leader) atomicAdd(&cnt[lbin], (unsigned)__popcll(mt));
                mask &= ~mt;
            }
        }
        __syncthreads();
        if (threadIdx.x == 0) {
            unsigned cum = 0;
            int bin = 0;
            for (int i = 255; i >= 0; --i) {
                if (cum + cnt[i] >= (unsigned)kk) { bin = i; break; }
                cum += cnt[i];
            }
            s_prefix = prefix | ((unsigned)bin << shift);
            s_k = kk - (int)cum;
        }
        __syncthreads();
        prefix = s_prefix;
        kk = s_k;
        __syncthreads();
    }

    unsigned kth = prefix;
    double sum = 0.0;
    int cg = 0;
    #pragma unroll
    for (int j = 0; j < 32; ++j) {
        unsigned u = key[j];
        if (u > kth) { sum += (double)__uint_as_float(u); ++cg; }
    }
    for (int off = 32; off; off >>= 1) {
        sum += __shfl_down(sum, off, 64);
        cg  += __shfl_down(cg, off, 64);
    }
    __shared__ double ssum[16];
    __shared__ int    scg[16];
    int wid = threadIdx.x >> 6;
    if ((threadIdx.x & 63) == 0) { ssum[wid] = sum; scg[wid] = cg; }
    __syncthreads();
    if (threadIdx.x == 0) {
        double tsum = 0.0; int tcg = 0;
        for (int i = 0; i < 16; ++i) { tsum += ssum[i]; tcg += scg[i]; }
        double total = tsum + (double)(k - tcg) * (double)__uint_as_float(kth);
        atomicAdd(&acc[2], total);
    }
}

// ---------------------------------------------------------------------------
// Kernel 4: finalize
// ---------------------------------------------------------------------------
__global__ void finalize_kernel(const int* __restrict__ num_pos,
                                const double* __restrict__ acc,
                                float* __restrict__ out) {
    if (threadIdx.x == 0 && blockIdx.x == 0) {
        int N = 0;
        for (int b = 0; b < B_; ++b) N += num_pos[b];
        double Nd = (double)N;
        out[0] = (float)(acc[0] / Nd);
        out[1] = (float)((acc[1] + acc[2]) / Nd);
    }
}

extern "C" void kernel_launch(void* const* d_in, const int* in_sizes, int n_in,
                              void* d_out, int out_size, void* d_ws, size_t ws_size,
                              hipStream_t stream) {
    const float* loc_data  = (const float*)d_in[0];
    const float* conf_data = (const float*)d_in[1];
    const float* priors    = (const float*)d_in[2];
    const float* targets   = (const float*)d_in[3];

    char* ws = (char*)d_ws;
    // layout: [bp_pack 8KB][num_pos 256B][acc 32B][pad to 512][rank 8MB]
    unsigned long long* bp_pack = (unsigned long long*)ws;
    int*    num_pos = (int*)(ws + 8192);
    double* acc     = (double*)(ws + 8192 + 256);
    float*  rank    = (float*)(ws + 8192 + 512);

    best_prior_kernel<<<dim3(O_, B_), 256, 0, stream>>>(priors, targets, bp_pack,
                                                        (int*)(ws + 8192));
    match_kernel<<<dim3(P_ / (256 * PPT), B_), 256, 0, stream>>>(
        loc_data, conf_data, priors, targets, bp_pack, rank, num_pos, acc);
    topk_kernel<<<B_, 1024, 0, stream>>>(rank, num_pos, acc);
    finalize_kernel<<<1, 64, 0, stream>>>(num_pos, acc, (float*)d_out);
}

// Round 4
// 131.804 us; speedup vs baseline: 2.0467x; 2.0467x over previous
//
#include <hip/hip_runtime.h>
#include <stdint.h>

#define B_ 64
#define P_ 32768
#define O_ 16
#define PPT 4                 // priors per thread in match_kernel

constexpr float OVERLAP_THRESH = 0.5f;
constexpr int   NEG_POS_RATIO  = 3;
constexpr float VAR0 = 0.1f;
constexpr float VAR1 = 0.2f;

// ---------------------------------------------------------------------------
// Kernel 1: per (b, truth o) find best prior index = argmax_p IoU(truth, prior)
// Tie-break: first (lowest) prior index, matching jnp.argmax. Packed key:
// (float_bits(iou) << 32) | ~p  — iou >= 0 so float bits are monotonic.
// Block (0,0) also zeroes the num_pos/acc scratch region (replaces memset).
// ---------------------------------------------------------------------------
__global__ __launch_bounds__(256)
void best_prior_kernel(const float* __restrict__ priors,
                       const float* __restrict__ targets,
                       unsigned long long* __restrict__ bp_pack,
                       int* __restrict__ zero_region) {
    if (blockIdx.x == 0 && blockIdx.y == 0 && threadIdx.x < 128)
        zero_region[threadIdx.x] = 0;

    int o = blockIdx.x;
    int b = blockIdx.y;
    const float* t = targets + (size_t)(b * O_ + o) * 5;
    float tx0 = t[0], ty0 = t[1], tx1 = t[2], ty1 = t[3];
    float area_t = (tx1 - tx0) * (ty1 - ty0);

    unsigned long long best = 0ull;
    for (int p = threadIdx.x; p < P_; p += blockDim.x) {
        float4 pr = ((const float4*)priors)[p];
        float px0 = pr.x - pr.z * 0.5f, py0 = pr.y - pr.w * 0.5f;
        float px1 = pr.x + pr.z * 0.5f, py1 = pr.y + pr.w * 0.5f;
        float area_p = (px1 - px0) * (py1 - py0);
        float ltx = fmaxf(tx0, px0), lty = fmaxf(ty0, py0);
        float rbx = fminf(tx1, px1), rby = fminf(ty1, py1);
        float w = fmaxf(rbx - ltx, 0.f), h = fmaxf(rby - lty, 0.f);
        float inter = w * h;
        float iou = inter / (area_t + area_p - inter);
        unsigned long long pack =
            ((unsigned long long)__float_as_uint(iou) << 32) | (unsigned)(~p);
        best = pack > best ? pack : best;
    }
    for (int off = 32; off; off >>= 1) {
        unsigned long long other = __shfl_down(best, off, 64);
        best = other > best ? other : best;
    }
    __shared__ unsigned long long s[4];
    int wid = threadIdx.x >> 6;
    if ((threadIdx.x & 63) == 0) s[wid] = best;
    __syncthreads();
    if (threadIdx.x == 0) {
        int nw = blockDim.x >> 6;
        for (int i = 1; i < nw; ++i) best = s[i] > best ? s[i] : best;
        bp_pack[b * O_ + o] = best;
    }
}

// ---------------------------------------------------------------------------
// Kernel 2: per (b, prior p): match, encode, smooth-L1, CE, rank_src.
// Division-free matching; truths-outer / priors-inner for ILP.
// ---------------------------------------------------------------------------
__device__ __forceinline__ float sl1(float d) {
    float ad = fabsf(d);
    return (ad < 1.f) ? 0.5f * d * d : ad - 0.5f;
}

__global__ __launch_bounds__(256)
void match_kernel(const float* __restrict__ loc_data,
                  const float* __restrict__ conf_data,
                  const float* __restrict__ priors,
                  const float* __restrict__ targets,
                  const unsigned long long* __restrict__ bp_pack,
                  float* __restrict__ rank,
                  int* __restrict__ num_pos,
                  double* __restrict__ acc) {
    int b = blockIdx.y;
    int p0 = blockIdx.x * (256 * PPT) + threadIdx.x;

    __shared__ float tr[O_][5];   // x0,y0,x1,y1,area
    __shared__ int   bpidx[O_];
    if (threadIdx.x < O_) {
        const float* t = targets + (size_t)(b * O_ + threadIdx.x) * 5;
        float x0 = t[0], y0 = t[1], x1 = t[2], y1 = t[3];
        tr[threadIdx.x][0] = x0; tr[threadIdx.x][1] = y0;
        tr[threadIdx.x][2] = x1; tr[threadIdx.x][3] = y1;
        tr[threadIdx.x][4] = (x1 - x0) * (y1 - y0);
        unsigned long long pk = bp_pack[b * O_ + threadIdx.x];
        bpidx[threadIdx.x] = (int)(~(unsigned)(pk & 0xffffffffull));
    }
    __syncthreads();

    float px0[PPT], py0[PPT], px1[PPT], py1[PPT], pa[PPT];
    float cx[PPT], cy[PPT], pz[PPT], pw[PPT];
    float2 cd[PPT];
    float ib[PPT], ub[PPT];
    int   idx[PPT], fidx[PPT];
    bool  fset[PPT];

    #pragma unroll
    for (int j = 0; j < PPT; ++j) {
        int p = p0 + j * 256;
        float4 pr = ((const float4*)priors)[p];
        cd[j] = ((const float2*)conf_data)[(size_t)b * P_ + p];
        cx[j] = pr.x; cy[j] = pr.y; pz[j] = pr.z; pw[j] = pr.w;
        px0[j] = pr.x - pr.z * 0.5f; py0[j] = pr.y - pr.w * 0.5f;
        px1[j] = pr.x + pr.z * 0.5f; py1[j] = pr.y + pr.w * 0.5f;
        pa[j]  = (px1[j] - px0[j]) * (py1[j] - py0[j]);
        ib[j] = 0.f; ub[j] = 1.f; idx[j] = 0; fidx[j] = 0; fset[j] = false;
    }

    #pragma unroll
    for (int o = 0; o < O_; ++o) {
        float tx0 = tr[o][0], ty0 = tr[o][1];
        float tx1 = tr[o][2], ty1 = tr[o][3], ta = tr[o][4];
        int bp = bpidx[o];
        #pragma unroll
        for (int j = 0; j < PPT; ++j) {
            float w = fmaxf(fminf(tx1, px1[j]) - fmaxf(tx0, px0[j]), 0.f);
            float h = fmaxf(fminf(ty1, py1[j]) - fmaxf(ty0, py0[j]), 0.f);
            float in_ = w * h;
            float un_ = ta + pa[j] - in_;
            bool gt = in_ * ub[j] > ib[j] * un_;
            ib[j]  = gt ? in_ : ib[j];
            ub[j]  = gt ? un_ : ub[j];
            idx[j] = gt ? o : idx[j];
            bool hit = (bp == p0 + j * 256);
            fidx[j] = hit ? o : fidx[j];
            fset[j] |= hit;
        }
    }

    double lld = 0.0, ce_pos = 0.0;
    int pc = 0;

    #pragma unroll
    for (int j = 0; j < PPT; ++j) {
        int p = p0 + j * 256;
        size_t gi = (size_t)b * P_ + p;
        bool pos = fset[j] || (2.0f * ib[j] >= ub[j]);
        int mi = fset[j] ? fidx[j] : idx[j];

        float m   = fmaxf(cd[j].x, cd[j].y);
        float ad  = fabsf(cd[j].x - cd[j].y);
        float lse = m + __logf(1.0f + __expf(-ad));
        float cgt = pos ? cd[j].y : cd[j].x;
        float ce  = lse - cgt;

        rank[gi] = pos ? 0.f : ce;

        if (pos) {
            float mx0 = tr[mi][0], my0 = tr[mi][1];
            float mx1 = tr[mi][2], my1 = tr[mi][3];
            float gcx = ((mx0 + mx1) * 0.5f - cx[j]) / (VAR0 * pz[j]);
            float gcy = ((my0 + my1) * 0.5f - cy[j]) / (VAR0 * pw[j]);
            float gw  = __logf((mx1 - mx0) / pz[j]) * (1.0f / VAR1);
            float gh  = __logf((my1 - my0) / pw[j]) * (1.0f / VAR1);
            float4 ld = ((const float4*)loc_data)[gi];
            float ll = sl1(ld.x - gcx) + sl1(ld.y - gcy) +
                       sl1(ld.z - gw)  + sl1(ld.w - gh);
            lld    += (double)ll;
            ce_pos += (double)ce;
            pc     += 1;
        }
    }

    for (int off = 32; off; off >>= 1) {
        lld    += __shfl_down(lld, off, 64);
        ce_pos += __shfl_down(ce_pos, off, 64);
        pc     += __shfl_down(pc, off, 64);
    }
    __shared__ double sll[4], sce[4];
    __shared__ int    spc[4];
    int wid = threadIdx.x >> 6;
    if ((threadIdx.x & 63) == 0) { sll[wid] = lld; sce[wid] = ce_pos; spc[wid] = pc; }
    __syncthreads();
    if (threadIdx.x == 0) {
        double tl = sll[0] + sll[1] + sll[2] + sll[3];
        double tc = sce[0] + sce[1] + sce[2] + sce[3];
        int    tp = spc[0] + spc[1] + spc[2] + spc[3];
        if (tl != 0.0) atomicAdd(&acc[0], tl);
        if (tc != 0.0) atomicAdd(&acc[1], tc);
        if (tp)        atomicAdd(&num_pos[b], tp);
    }
}

// ---------------------------------------------------------------------------
// Kernel 3: per batch, exact top-k sum via 8-bit radix select.
// Keys register-resident (32/thread, one global read). Histogram: plain LDS
// atomics (spread over ~50 banks-distinct addresses -> ~1-2us). Bin selection:
// single-wave suffix-scan in registers (shfl), no serial 256-iter loop.
// top-k sum = sum(values > kth) + (k - count_greater) * kth  (tie-exact).
// ---------------------------------------------------------------------------
__global__ __launch_bounds__(1024)
void topk_kernel(const float* __restrict__ rank,
                 const int* __restrict__ num_pos,
                 double* __restrict__ acc) {
    int b  = blockIdx.x;
    int np = num_pos[b];
    int k  = min(NEG_POS_RATIO * np, P_ - 1);
    if (k <= 0) return;

    const uint4* r4 = (const uint4*)(rank + (size_t)b * P_);
    unsigned key[32];
    #pragma unroll
    for (int j = 0; j < 8; ++j) {
        uint4 v = r4[j * 1024 + threadIdx.x];
        key[j * 4 + 0] = v.x; key[j * 4 + 1] = v.y;
        key[j * 4 + 2] = v.z; key[j * 4 + 3] = v.w;
    }

    __shared__ unsigned cnt[256];
    __shared__ unsigned s_prefix;
    __shared__ int      s_k;

    unsigned prefix = 0;
    int kk = k;
    for (int level = 0; level < 4; ++level) {
        int shift = 24 - level * 8;
        if (threadIdx.x < 256) cnt[threadIdx.x] = 0;
        __syncthreads();
        unsigned hi_mask = (level == 0) ? 0u : (0xffffffffu << (shift + 8));
        #pragma unroll
        for (int j = 0; j < 32; ++j) {
            unsigned u = key[j];
            if ((u & hi_mask) == prefix) atomicAdd(&cnt[(u >> shift) & 255], 1u);
        }
        __syncthreads();
        // single-wave suffix scan: lane t owns bins [4t, 4t+3]
        if (threadIdx.x < 64) {
            int lane = threadIdx.x;
            unsigned c0 = cnt[4 * lane + 0], c1 = cnt[4 * lane + 1];
            unsigned c2 = cnt[4 * lane + 2], c3 = cnt[4 * lane + 3];
            unsigned L3 = c3, L2 = c2 + L3, L1 = c1 + L2, L0 = c0 + L1;
            unsigned g = L0, G = g;
            #pragma unroll
            for (int off = 1; off < 64; off <<= 1) {
                unsigned gr = __shfl_down(G, off, 64);
                if (lane + off < 64) G += gr;
            }
            unsigned Gn = G - g;            // suffix sum of groups > lane
            unsigned S0 = L0 + Gn, S1 = L1 + Gn, S2 = L2 + Gn, S3 = L3 + Gn;
            unsigned ukk = (unsigned)kk;
            // unique bin: largest i with S[i] >= kk (S non-increasing in i)
            if      (S3 >= ukk && Gn < ukk) { s_prefix = prefix | ((4u*lane+3) << shift); s_k = kk - (int)Gn; }
            else if (S2 >= ukk && S3 < ukk) { s_prefix = prefix | ((4u*lane+2) << shift); s_k = kk - (int)S3; }
            else if (S1 >= ukk && S2 < ukk) { s_prefix = prefix | ((4u*lane+1) << shift); s_k = kk - (int)S2; }
            else if (S0 >= ukk && S1 < ukk) { s_prefix = prefix | ((4u*lane+0) << shift); s_k = kk - (int)S1; }
        }
        __syncthreads();
        prefix = s_prefix;
        kk = s_k;
    }

    unsigned kth = prefix;  // exact bits of the k-th largest value
    double sum = 0.0;
    int cg = 0;
    #pragma unroll
    for (int j = 0; j < 32; ++j) {
        unsigned u = key[j];
        if (u > kth) { sum += (double)__uint_as_float(u); ++cg; }
    }
    for (int off = 32; off; off >>= 1) {
        sum += __shfl_down(sum, off, 64);
        cg  += __shfl_down(cg, off, 64);
    }
    __shared__ double ssum[16];
    __shared__ int    scg[16];
    int wid = threadIdx.x >> 6;
    if ((threadIdx.x & 63) == 0) { ssum[wid] = sum; scg[wid] = cg; }
    __syncthreads();
    if (threadIdx.x == 0) {
        double tsum = 0.0; int tcg = 0;
        for (int i = 0; i < 16; ++i) { tsum += ssum[i]; tcg += scg[i]; }
        double total = tsum + (double)(k - tcg) * (double)__uint_as_float(kth);
        atomicAdd(&acc[2], total);
    }
}

// ---------------------------------------------------------------------------
// Kernel 4: finalize
// ---------------------------------------------------------------------------
__global__ void finalize_kernel(const int* __restrict__ num_pos,
                                const double* __restrict__ acc,
                                float* __restrict__ out) {
    if (threadIdx.x == 0 && blockIdx.x == 0) {
        int N = 0;
        for (int b = 0; b < B_; ++b) N += num_pos[b];
        double Nd = (double)N;
        out[0] = (float)(acc[0] / Nd);
        out[1] = (float)((acc[1] + acc[2]) / Nd);
    }
}

extern "C" void kernel_launch(void* const* d_in, const int* in_sizes, int n_in,
                              void* d_out, int out_size, void* d_ws, size_t ws_size,
                              hipStream_t stream) {
    const float* loc_data  = (const float*)d_in[0];
    const float* conf_data = (const float*)d_in[1];
    const float* priors    = (const float*)d_in[2];
    const float* targets   = (const float*)d_in[3];

    char* ws = (char*)d_ws;
    // layout: [bp_pack 8KB][num_pos 256B][acc 32B][pad to 512][rank 8MB]
    unsigned long long* bp_pack = (unsigned long long*)ws;
    int*    num_pos = (int*)(ws + 8192);
    double* acc     = (double*)(ws + 8192 + 256);
    float*  rank    = (float*)(ws + 8192 + 512);

    best_prior_kernel<<<dim3(O_, B_), 256, 0, stream>>>(priors, targets, bp_pack,
                                                        (int*)(ws + 8192));
    match_kernel<<<dim3(P_ / (256 * PPT), B_), 256, 0, stream>>>(
        loc_data, conf_data, priors, targets, bp_pack, rank, num_pos, acc);
    topk_kernel<<<B_, 1024, 0, stream>>>(rank, num_pos, acc);
    finalize_kernel<<<1, 64, 0, stream>>>(num_pos, acc, (float*)d_out);
}